// Round 11
// baseline (125.758 us; speedup 1.0000x reference)
//
#include <hip/hip_runtime.h>
#include <hip/hip_fp16.h>

#define N_NODES 50000
#define DIM 64
#define CB 391          // coarse buckets = ceil(N/128); bucket = dst >> 7
#define SUBS 8          // sub-regions per bucket, keyed by blockIdx&7 (~XCD)
#define CAPS 384        // per-(bucket,sub) capacity (mean 256, sd 16 -> +8 sd)
#define EB 1024         // edges per partition block
#define SCAP 1344       // per-half-bucket LDS edge capacity (mean 1023, +10 sd)
#define PLW 68          // pooled LDS row stride in floats (+4: bank spread)

typedef _Float16 half8 __attribute__((ext_vector_type(8)));
typedef float floatx4 __attribute__((ext_vector_type(4)));

// Workspace byte offsets (16B-aligned).
#define WS_CURSOR  0                          // SUBS*CB ints = 12512 B
#define WS_COARSE  16384                      // CB*SUBS*CAPS uint = 4,804,608
#define WS_WT      (WS_COARSE + 4804608)      // DIM*DIM f16 = 8,192

// ---------------------------------------------------------------------------
// Prep: blocks [0,pa) partition edges into (bucket, sub=blockIdx&7) regions.
// Same-sub blocks land on the same XCD under round-robin dispatch, so each
// (bucket,sub) region's 64B lines are written by one XCD's L2 only (write
// combining; no IF-fabric line ping-pong).  Correct regardless of the real
// block->XCD map: sub only needs to be block-uniform.  Last block builds
// W^T fp16.  No fp16 x copy anymore (R5 proved the gather isn't BW-bound).
// ---------------------------------------------------------------------------
__global__ void __launch_bounds__(256) prep_kernel(
        const float* __restrict__ W,
        const int* __restrict__ edge_src, const int* __restrict__ edge_dst,
        int* __restrict__ cursor2, unsigned int* __restrict__ coarse2,
        _Float16* __restrict__ wt, int E, int pa) {
    int b = blockIdx.x, t = threadIdx.x;
    if (b < pa) {
        __shared__ int lhist[CB];
        __shared__ int lbase[CB];
        for (int i = t; i < CB; i += 256) lhist[i] = 0;
        __syncthreads();

        int sub = b & (SUBS - 1);
        int base = b * EB;
        int end = base + EB; if (end > E) end = E;

        for (int i = base + t; i < end; i += 256) {
            atomicAdd(&lhist[edge_dst[i] >> 7], 1);
        }
        __syncthreads();
        for (int i = t; i < CB; i += 256) {
            lbase[i] = atomicAdd(&cursor2[sub * CB + i], lhist[i]);
            lhist[i] = 0;
        }
        __syncthreads();
        for (int i = base + t; i < end; i += 256) {
            int s = edge_src[i];
            int d = edge_dst[i];
            int bk = d >> 7;
            int r = atomicAdd(&lhist[bk], 1);
            coarse2[((size_t)bk * SUBS + sub) * CAPS + lbase[bk] + r] =
                ((unsigned int)s << 7) | (unsigned int)(d & 127);
        }
    } else {
        #pragma unroll
        for (int i = 0; i < 16; ++i) {        // W^T: wt[n*64+k] = W[k*64+n]
            int idx = t * 16 + i;
            int n = idx >> 6, k = idx & 63;
            wt[idx] = (_Float16)W[k * DIM + n];
        }
    }
}

// ---------------------------------------------------------------------------
// Fused sort + gather + project.  Two 256-thread blocks per bucket; block b
// owns nodes [b*64, b*64+64):
//  1. Filter the bucket's 8 sub-lists to our half; 64-bin LDS hist +
//     wave shfl-scan + scatter into sedges (int LDS atomics only).
//  2. 16 groups x 16 lanes, 4 nodes/group: broadcast ds_read of edge id,
//     float4 gather of the full fp32 row (256 B/edge across the group),
//     4 edges in flight, fp32 register accumulate + residual, one plain
//     ds_write per pooled row chunk (stride-68 fp32 tile).
//  3. 4 waves x 16 nodes: in-register fp32->f16 A-frags from the LDS tile,
//     B-frags contiguous from W^T (L2-hot), 2x mfma_f32_16x16x32_f16 per
//     N-tile, fused bias + /deg + ReLU -> out.
// ---------------------------------------------------------------------------
__global__ void __launch_bounds__(256) fused_kernel(
        const float* __restrict__ x,
        const _Float16* __restrict__ wt,
        const float* __restrict__ bias,
        const float* __restrict__ deg,
        const int* __restrict__ cursor2,
        const unsigned int* __restrict__ coarse2,
        float* __restrict__ out) {
    __shared__ unsigned int sedges[SCAP];
    __shared__ float pl[64 * PLW];
    __shared__ int hist[64];
    __shared__ int excl[64];
    __shared__ int cur[64];

    int t = threadIdx.x;
    int b = blockIdx.x;
    int bucket = b >> 1;
    int half = b & 1;
    int nb = b * 64;                       // global node base for this block

    // --- 1a. histogram over our 64 local bins, across the 8 sub-lists ---
    if (t < 64) hist[t] = 0;
    __syncthreads();
    for (int s = 0; s < SUBS; ++s) {
        int cs = cursor2[s * CB + bucket];
        const unsigned int* p = coarse2 + ((size_t)bucket * SUBS + s) * CAPS;
        for (int i = t; i < cs; i += 256) {
            unsigned int e = p[i];
            int loc = (int)(e & 127u);
            if ((loc >> 6) == half) atomicAdd(&hist[loc & 63], 1);
        }
    }
    __syncthreads();

    // --- 1b. wave shfl-scan (threads 0..63 = wave 0) ---
    if (t < 64) {
        int v = hist[t];
        int s = v;
        #pragma unroll
        for (int off = 1; off < 64; off <<= 1) {
            int u = __shfl_up(s, off);
            if (t >= off) s += u;
        }
        excl[t] = s - v;
        cur[t]  = s - v;
    }
    __syncthreads();

    // --- 1c. scatter src ids into locally-sorted order ---
    for (int s = 0; s < SUBS; ++s) {
        int cs = cursor2[s * CB + bucket];
        const unsigned int* p = coarse2 + ((size_t)bucket * SUBS + s) * CAPS;
        for (int i = t; i < cs; i += 256) {
            unsigned int e = p[i];
            int loc = (int)(e & 127u);
            if ((loc >> 6) == half) {
                int q = atomicAdd(&cur[loc & 63], 1);
                sedges[q] = e >> 7;
            }
        }
    }
    __syncthreads();

    // --- 2. gather: 16 groups of 16 lanes, 4 nodes per group ---
    int g = t >> 4;          // group 0..15
    int c = t & 15;          // float4 chunk within the 64-float row
    #pragma unroll
    for (int pass = 0; pass < 4; ++pass) {
        int loc = g + pass * 16;
        int node = nb + loc;
        float4 acc = make_float4(0.f, 0.f, 0.f, 0.f);
        int off = excl[loc];
        int ct = (node < N_NODES) ? hist[loc] : 0;
        int k = 0;
        for (; k + 4 <= ct; k += 4) {       // 4 edges in flight
            int s0 = (int)sedges[off + k + 0];
            int s1 = (int)sedges[off + k + 1];
            int s2 = (int)sedges[off + k + 2];
            int s3 = (int)sedges[off + k + 3];
            float4 v0 = *reinterpret_cast<const float4*>(x + (size_t)s0 * DIM + c * 4);
            float4 v1 = *reinterpret_cast<const float4*>(x + (size_t)s1 * DIM + c * 4);
            float4 v2 = *reinterpret_cast<const float4*>(x + (size_t)s2 * DIM + c * 4);
            float4 v3 = *reinterpret_cast<const float4*>(x + (size_t)s3 * DIM + c * 4);
            acc.x += v0.x + v1.x + v2.x + v3.x;
            acc.y += v0.y + v1.y + v2.y + v3.y;
            acc.z += v0.z + v1.z + v2.z + v3.z;
            acc.w += v0.w + v1.w + v2.w + v3.w;
        }
        for (; k < ct; ++k) {
            int s0 = (int)sedges[off + k];
            float4 v0 = *reinterpret_cast<const float4*>(x + (size_t)s0 * DIM + c * 4);
            acc.x += v0.x; acc.y += v0.y; acc.z += v0.z; acc.w += v0.w;
        }
        if (node < N_NODES) {
            const float4 r = *reinterpret_cast<const float4*>(
                x + (size_t)node * DIM + c * 4);
            float* p = &pl[loc * PLW + c * 4];
            p[0] = acc.x + r.x; p[1] = acc.y + r.y;
            p[2] = acc.z + r.z; p[3] = acc.w + r.w;
        }
    }
    __syncthreads();

    // --- 3. MFMA projection: wave wv handles nodes lbase..lbase+15 ---
    int wv = t >> 6;
    int lane = t & 63;
    int m = lane & 15;
    int q = lane >> 4;
    int lbase = wv * 16;

    const float* ap = &pl[(lbase + m) * PLW];
    half8 a0, a1;
    #pragma unroll
    for (int j = 0; j < 8; ++j) a0[j] = (_Float16)ap[q * 8 + j];
    #pragma unroll
    for (int j = 0; j < 8; ++j) a1[j] = (_Float16)ap[32 + q * 8 + j];

    floatx4 acc4[4];
    #pragma unroll
    for (int tt = 0; tt < 4; ++tt) {
        half8 b0 = *reinterpret_cast<const half8*>(wt + (size_t)(tt * 16 + m) * DIM + q * 8);
        half8 b1 = *reinterpret_cast<const half8*>(wt + (size_t)(tt * 16 + m) * DIM + q * 8 + 32);
        floatx4 cfrag = {0.f, 0.f, 0.f, 0.f};
        cfrag = __builtin_amdgcn_mfma_f32_16x16x32_f16(a0, b0, cfrag, 0, 0, 0);
        cfrag = __builtin_amdgcn_mfma_f32_16x16x32_f16(a1, b1, cfrag, 0, 0, 0);
        acc4[tt] = cfrag;
    }

    #pragma unroll
    for (int r = 0; r < 4; ++r) {
        int row = q * 4 + r;
        int node = nb + lbase + row;
        if (node < N_NODES) {
            float inv = 1.0f / deg[node];
            #pragma unroll
            for (int tt = 0; tt < 4; ++tt) {
                float v = (acc4[tt][r] + bias[tt * 16 + m]) * inv;
                out[(size_t)node * DIM + tt * 16 + m] = fmaxf(v, 0.f);
            }
        }
    }
}

extern "C" void kernel_launch(void* const* d_in, const int* in_sizes, int n_in,
                              void* d_out, int out_size, void* d_ws, size_t ws_size,
                              hipStream_t stream) {
    const float* x        = (const float*)d_in[0];
    const float* weight   = (const float*)d_in[1];
    const float* bias     = (const float*)d_in[2];
    const float* node_deg = (const float*)d_in[3];
    const int*   edge_src = (const int*)d_in[4];
    const int*   edge_dst = (const int*)d_in[5];
    float* out = (float*)d_out;
    const int E = in_sizes[4];

    char* ws = (char*)d_ws;
    int*          cursor2 = (int*)(ws + WS_CURSOR);
    unsigned int* coarse2 = (unsigned int*)(ws + WS_COARSE);
    _Float16*     wt      = (_Float16*)(ws + WS_WT);

    hipMemsetAsync(cursor2, 0, SUBS * CB * sizeof(int), stream);

    int pa = (E + EB - 1) / EB;               // 782 partition blocks
    prep_kernel<<<pa + 1, 256, 0, stream>>>(
        weight, edge_src, edge_dst, cursor2, coarse2, wt, E, pa);

    fused_kernel<<<2 * CB, 256, 0, stream>>>(
        x, wt, bias, node_deg, cursor2, coarse2, out);
}